// Round 9
// baseline (3190.080 us; speedup 1.0000x reference)
//
#include <hip/hip_runtime.h>
#include <cstdint>
#include <cstddef>

#define B_   256
#define T_   512
#define E_   128
#define H_   256

typedef _Float16 f16x8 __attribute__((ext_vector_type(8)));
typedef _Float16 f16x4 __attribute__((ext_vector_type(4)));
typedef float    f32x4 __attribute__((ext_vector_type(4)));

// rcp-based fast activations: no div sequence (v_div ~8 ops vs v_rcp 1).
// tanh(x) = 1 - 2/(1+e^{2x}) saturates correctly at +-inf without clamping.
__device__ __forceinline__ float sigm(float x) {
  return __builtin_amdgcn_rcpf(1.f + __expf(-x));
}
__device__ __forceinline__ float tanh_(float x) {
  float e = __expf(2.f * x);
  return 1.f - 2.f * __builtin_amdgcn_rcpf(1.f + e);
}
__device__ __forceinline__ void poll_ge(const int* p, int v) {
  while (__hip_atomic_load(p, __ATOMIC_ACQUIRE, __HIP_MEMORY_SCOPE_AGENT) < v)
    __builtin_amdgcn_s_sleep(4);
}

// ---------------- prep: swizzle weights to MFMA fragment order (fp16) -----------------------
// WSW[dir][kc(12)][tile(48)][lane(64)][8] fp16. kc 0..7: W_hh (K=256), kc 8..11: W_ih (K=128).
// Fragment: lane l supplies W[tile*16+(l&15)][k=(l>>4)*8+j] (8 k-consecutive of row-major W).
// Tiles 0..15 = r rows, 16..31 = z, 32..47 = n.  (verified layout, prior rounds)
// Block 288 additionally does the length-sort + flag init (merged former sort_kernel).
__global__ __launch_bounds__(256) void prep_kernel(
    const float* __restrict__ whhf, const float* __restrict__ whhb,
    const float* __restrict__ wihf, const float* __restrict__ wihb,
    _Float16* __restrict__ WSW,
    const int* __restrict__ lens, int* __restrict__ order, int* __restrict__ flags)
{
  if (blockIdx.x == 288) {
    // rank rows by length (desc) + init flags (ws is re-poisoned each call)
    // FLAGS: [0..1023]    ready slots (g*32 + half*16), init 0
    //        [1024..1535] done slots (1024 + g*16 + hf*8), init -1
    //        [1536..1599] h-exchange counters (1536 + g*2 + hf), init -1
    int i = threadIdx.x;                      // one block of 256
    for (int k = i; k < 1024; k += 256) flags[k] = 0;
    for (int k = i; k < 640;  k += 256) flags[1024 + k] = -1;
    int li = lens[i];
    int rank = 0;
    for (int k = 0; k < B_; ++k) {
      int lk = lens[k];
      rank += (lk > li) || (lk == li && k < i);
    }
    order[rank] = i;
    return;
  }
  int idx = blockIdx.x * 256 + threadIdx.x;   // 288 blocks -> 73728 exactly
  int lane = idx & 63;
  int tile = (idx >> 6) % 48;
  int kc   = (idx / 3072) % 12;
  int dir  = idx / 36864;
  int ncol = tile * 16 + (lane & 15);
  int quad = lane >> 4;
  const float* src;
  if (kc < 8) {
    const float* w = dir ? whhb : whhf;       // [768][256] row-major
    src = w + (size_t)ncol * H_ + kc * 32 + quad * 8;
  } else {
    const float* w = dir ? wihb : wihf;       // [768][128] row-major
    src = w + (size_t)ncol * E_ + (kc - 8) * 32 + quad * 8;
  }
  f16x8 v;
  #pragma unroll
  for (int j = 0; j < 8; ++j) v[j] = (_Float16)src[j];
  *(f16x8*)(WSW + (size_t)idx * 8) = v;
}

// ---------------- fused scan + xp producers, 128 blocks x 512 threads ------------------------
// R8 lesson: full weight residency on ONE CU/group is register-infeasible (192 AGPR + ~80
// working > 256/wave at 2 waves/SIMD -> spill, 1923us). R9: SPLIT each group's recurrence
// across TWO CUs (halves of the 256 hidden units). Per CU: 24 tiles -> 3 tiles/wave = 24
// frags = 96 AGPR (fully resident, ~90 arch regs free); MFMA 192/CU (~930cyc); LDS = own-half
// h only (32 ds_read_b128/CU/step). Halves exchange h (4KB) per step through the XCD-shared
// L2 (consumer blocks g and g+32 both map to XCD g%8), double-buffered HX + per-half step
// counter, same release/acquire-poll idiom as the proven XP protocol. Skew <= 1 step, so
// 2 buffers suffice; partner half is loaded straight global->regs (no LDS relay).
// blocks 0..63 consumers: (g = bid&31, hf = bid>>5). blocks 64..127 producers (unchanged
// structure; poll BOTH halves' done counters).
#define XPSLAB 196608        // halfs per (buf,g): 16 s x 12288
__global__ __launch_bounds__(512, 1) void fused_kernel(
    const _Float16* __restrict__ WSW, const int* __restrict__ seqs,
    const float* __restrict__ embed,
    const float* __restrict__ bihf, const float* __restrict__ bhhf,
    const float* __restrict__ bihb, const float* __restrict__ bhhb,
    const int* __restrict__ lens, const int* __restrict__ order,
    _Float16* __restrict__ XP, _Float16* __restrict__ HX,
    int* __restrict__ FLAGS, float* __restrict__ hcat)
{
  // union'd LDS arena:
  // consumer: [0,8704) hbuf [buf2][chain16][136]
  // producer: [0,17408) xstage[4][16][136]
  __shared__ __align__(16) char smem[17408];
  __shared__ int s_row[16], s_len[16];

  const int bid = blockIdx.x, tid = threadIdx.x;
  const int w = tid >> 6, lane = tid & 63, lm = lane & 15, lq = lane >> 4;

  if (bid < 64) {
    // ================= CONSUMER (g, hf) =================
    const int g = bid & 31, hf = bid >> 5, po = 1 - hf;
    const int dir = g & 1, grp = g >> 1;
    _Float16* hb = (_Float16*)smem;                        // [buf][chain][136]
    if (tid < 16) { int r = order[grp * 16 + tid]; s_row[tid] = r; s_len[tid] = lens[r]; }
    for (int i = tid; i < 2 * 16 * 136; i += 512) hb[i] = (_Float16)0.f;
    {                                                      // zero own HX buf0 (h(0) = 0)
      f16x4 z4 = {};
      *(f16x4*)(HX + ((size_t)(g * 2 + hf) * 2 + 0) * 2048 + tid * 4) = z4;
    }
    // this wave's 3 tiles (r,z,n of units hf*128 + w*16 ..+15): 24 frags -> 96 AGPR
    const _Float16* wsd = WSW + (size_t)dir * 294912 + (size_t)lane * 8;
    f16x8 whr[8], whz[8], whn[8];
    #pragma unroll
    for (int kc = 0; kc < 8; ++kc) {
      whr[kc] = *(const f16x8*)(wsd + (size_t)kc * 24576 + (hf * 8 + w)      * 512);
      asm volatile("" : "+a"(whr[kc]));
      whz[kc] = *(const f16x8*)(wsd + (size_t)kc * 24576 + (16 + hf * 8 + w) * 512);
      asm volatile("" : "+a"(whz[kc]));
      whn[kc] = *(const f16x8*)(wsd + (size_t)kc * 24576 + (32 + hf * 8 + w) * 512);
      asm volatile("" : "+a"(whn[kc]));
    }
    const float* bhh = dir ? bhhb : bhhf;
    f16x4 bhn;                                             // n-gate b_hh for this wave's units
    {
      float4 b = *(const float4*)(bhh + 512 + hf * 128 + w * 16 + lq * 4);
      bhn[0] = (_Float16)b.x; bhn[1] = (_Float16)b.y;
      bhn[2] = (_Float16)b.z; bhn[3] = (_Float16)b.w;
    }
    __syncthreads();                                       // HX-zero drained, LDS zero visible
    int* mineC = FLAGS + 1536 + g * 2 + hf;
    const int* peerC = FLAGS + 1536 + g * 2 + po;
    if (tid == 0)
      __hip_atomic_store(mineC, 0, __ATOMIC_RELEASE, __HIP_MEMORY_SCOPE_AGENT);

    const int len_l = s_len[lm];
    int ml = 1;
    #pragma unroll
    for (int i = 0; i < 16; ++i) ml = max(ml, s_len[i]);

    int* doneP  = FLAGS + 1024 + g * 16 + hf * 8;
    const int* readyA = FLAGS + g * 32;
    const int* readyB = FLAGS + g * 32 + 16;
    float h32r[4] = {};

    for (int t = 0; t < ml; ++t) {
      if (tid == 0) {
        if ((t & 15) == 0) {                   // chunk boundary (XP protocol, unchanged)
          if (t) __hip_atomic_store(doneP, (t >> 4) - 1,
                                    __ATOMIC_RELEASE, __HIP_MEMORY_SCOPE_AGENT);
          poll_ge(readyA, (t >> 4) + 1);
          poll_ge(readyB, (t >> 4) + 1);
        }
        poll_ge(peerC, t);                     // partner published h(t)
      }
      __syncthreads();
      // partner-half h: straight global->regs from XCD-local L2 (4 x f16x8)
      const _Float16* hp = HX + ((size_t)(g * 2 + po) * 2 + (t & 1)) * 2048
                           + lm * 128 + lq * 8;
      f16x8 hp0 = *(const f16x8*)(hp);
      f16x8 hp1 = *(const f16x8*)(hp + 32);
      f16x8 hp2 = *(const f16x8*)(hp + 64);
      f16x8 hp3 = *(const f16x8*)(hp + 96);
      // xp for this step (this half's 3 tiles)
      const _Float16* sb = XP + ((size_t)((((t >> 4) & 1) * 32 + g)) * 16 + (t & 15)) * 12288
                           + lq * 64 + lm * 4;
      f16x4 xr = *(const f16x4*)(sb + (hf * 8 + w)      * 256);
      f16x4 xz = *(const f16x4*)(sb + (16 + hf * 8 + w) * 256);
      f16x4 xn = *(const f16x4*)(sb + (32 + hf * 8 + w) * 256);

      f32x4 ar = {}, az = {}, an;
      #pragma unroll
      for (int i = 0; i < 4; ++i) an[i] = (float)bhn[i];   // b_hh_n folded into C-init

      // own half first (LDS, fast): global kc = hf*4 + kco
      const _Float16* hrow = hb + ((size_t)(t & 1) * 16 + lm) * 136 + lq * 8;
      #pragma unroll
      for (int kco = 0; kco < 4; ++kco) {
        f16x8 hfr = *(const f16x8*)(hrow + kco * 32);
        ar = __builtin_amdgcn_mfma_f32_16x16x32_f16(whr[hf * 4 + kco], hfr, ar, 0, 0, 0);
        az = __builtin_amdgcn_mfma_f32_16x16x32_f16(whz[hf * 4 + kco], hfr, az, 0, 0, 0);
        an = __builtin_amdgcn_mfma_f32_16x16x32_f16(whn[hf * 4 + kco], hfr, an, 0, 0, 0);
      }
      // partner half: global kc = po*4 + kcp
      ar = __builtin_amdgcn_mfma_f32_16x16x32_f16(whr[po * 4 + 0], hp0, ar, 0, 0, 0);
      az = __builtin_amdgcn_mfma_f32_16x16x32_f16(whz[po * 4 + 0], hp0, az, 0, 0, 0);
      an = __builtin_amdgcn_mfma_f32_16x16x32_f16(whn[po * 4 + 0], hp0, an, 0, 0, 0);
      ar = __builtin_amdgcn_mfma_f32_16x16x32_f16(whr[po * 4 + 1], hp1, ar, 0, 0, 0);
      az = __builtin_amdgcn_mfma_f32_16x16x32_f16(whz[po * 4 + 1], hp1, az, 0, 0, 0);
      an = __builtin_amdgcn_mfma_f32_16x16x32_f16(whn[po * 4 + 1], hp1, an, 0, 0, 0);
      ar = __builtin_amdgcn_mfma_f32_16x16x32_f16(whr[po * 4 + 2], hp2, ar, 0, 0, 0);
      az = __builtin_amdgcn_mfma_f32_16x16x32_f16(whz[po * 4 + 2], hp2, az, 0, 0, 0);
      an = __builtin_amdgcn_mfma_f32_16x16x32_f16(whn[po * 4 + 2], hp2, an, 0, 0, 0);
      ar = __builtin_amdgcn_mfma_f32_16x16x32_f16(whr[po * 4 + 3], hp3, ar, 0, 0, 0);
      az = __builtin_amdgcn_mfma_f32_16x16x32_f16(whz[po * 4 + 3], hp3, az, 0, 0, 0);
      an = __builtin_amdgcn_mfma_f32_16x16x32_f16(whn[po * 4 + 3], hp3, an, 0, 0, 0);

      // epilogue: lane = (chain lm, units hf*128 + w*16 + lq*4 + i)
      f16x4 pk;
      #pragma unroll
      for (int i = 0; i < 4; ++i) {
        float r = sigm((float)xr[i] + ar[i]);
        float z = sigm((float)xz[i] + az[i]);
        float n = tanh_((float)xn[i] + r * an[i]);
        float hn = (t < len_l) ? (n + z * (h32r[i] - n)) : h32r[i];
        h32r[i] = hn;
        pk[i] = (_Float16)hn;
      }
      *(f16x4*)(hb + ((size_t)((t + 1) & 1) * 16 + lm) * 136 + w * 16 + lq * 4) = pk;
      *(f16x4*)(HX + ((size_t)(g * 2 + hf) * 2 + ((t + 1) & 1)) * 2048
                + lm * 128 + w * 16 + lq * 4) = pk;
      __syncthreads();                         // drains LDS + HX stores (vmcnt0 at barrier)
      if (tid == 0)
        __hip_atomic_store(mineC, t + 1, __ATOMIC_RELEASE, __HIP_MEMORY_SCOPE_AGENT);
    }
    if (tid == 0)
      __hip_atomic_store(doneP, 999, __ATOMIC_RELEASE, __HIP_MEMORY_SCOPE_AGENT);
    {
      const int rowb = s_row[lm];
      float4 o; o.x = h32r[0]; o.y = h32r[1]; o.z = h32r[2]; o.w = h32r[3];
      *(float4*)(&hcat[(size_t)rowb * (2 * H_) + dir * H_ + hf * 128 + w * 16 + lq * 4]) = o;
    }
  } else {
    // ================= PRODUCER =================
    // XCD-matched mapping: k = bid-64; bid%8 == k%8 == g%8 -> same L2 as consumer pair g.
    const int k_ = bid - 64;
    const int g = (k_ & 7) + 8 * (k_ >> 4), half = (k_ >> 3) & 1;
    const int dir = g & 1, grp = g >> 1;
    _Float16* xs = (_Float16*)smem;                        // [sb4][chain16][136]
    if (tid < 16) { int r = order[grp * 16 + tid]; s_row[tid] = r; s_len[tid] = lens[r]; }
    __syncthreads();
    int ml = 1;
    #pragma unroll
    for (int i = 0; i < 16; ++i) ml = max(ml, s_len[i]);
    const int nch = (ml + 15) >> 4;

    const int chain = tid >> 5, q = tid & 31;  // x-staging: 32 threads/chain
    const int rowb = s_row[chain], lenr = s_len[chain];
    const _Float16* wsd = WSW + (size_t)dir * 294912 + (size_t)lane * 8;
    const float* bih = dir ? bihb : bihf;
    const float* bhh = dir ? bhhb : bhhf;
    const int* doneA = FLAGS + 1024 + g * 16;
    const int* doneB = FLAGS + 1024 + g * 16 + 8;
    int* readyP = FLAGS + g * 32 + half * 16;

    // hoist this wave's 6 tiles (w, w+8, ..., w+40): weights + biases to registers
    f16x8 wA[6][4];
    float bb[6][4];
    #pragma unroll
    for (int ti = 0; ti < 6; ++ti) {
      const int tile = w + 8 * ti;
      #pragma unroll
      for (int kc = 0; kc < 4; ++kc)
        wA[ti][kc] = *(const f16x8*)(wsd + (size_t)(8 + kc) * 24576 + tile * 512);
      float4 bias = *(const float4*)(bih + tile * 16 + lq * 4);
      if (tile < 32) {                         // fold b_hh into r,z xp (n stays separate)
        float4 b2 = *(const float4*)(bhh + tile * 16 + lq * 4);
        bias.x += b2.x; bias.y += b2.y; bias.z += b2.z; bias.w += b2.w;
      }
      bb[ti][0] = bias.x; bb[ti][1] = bias.y; bb[ti][2] = bias.z; bb[ti][3] = bias.w;
    }

    for (int c = 0; c < nch; ++c) {
      if (c >= 2) {
        if (tid == 0) { poll_ge(doneA, c - 2); poll_ge(doneB, c - 2); }
        __syncthreads();
      }
      _Float16* slab = XP + (size_t)((c & 1) * 32 + g) * XPSLAB;
      #pragma unroll
      for (int batch = 0; batch < 2; ++batch) {
        #pragma unroll
        for (int sb = 0; sb < 4; ++sb) {       // stage x for 4 s-values
          int s = c * 16 + half * 8 + batch * 4 + sb;
          int p = dir ? (lenr - 1 - s) : s;
          p = min(max(p, 0), T_ - 1);
          int tok = seqs[(size_t)rowb * T_ + p];
          float4 f = *(const float4*)(embed + (size_t)tok * E_ + q * 4);
          f16x4 h4; h4[0] = (_Float16)f.x; h4[1] = (_Float16)f.y;
          h4[2] = (_Float16)f.z; h4[3] = (_Float16)f.w;
          *(f16x4*)(xs + ((size_t)sb * 16 + chain) * 136 + q * 4) = h4;
        }
        __syncthreads();
        f16x8 bx[4][4];
        #pragma unroll
        for (int sb = 0; sb < 4; ++sb)
          #pragma unroll
          for (int kc = 0; kc < 4; ++kc)
            bx[sb][kc] = *(const f16x8*)(xs + ((size_t)sb * 16 + lm) * 136 + kc * 32 + lq * 8);
        #pragma unroll
        for (int ti = 0; ti < 6; ++ti) {       // tiles partitioned across waves
          const int tile = w + 8 * ti;
          f32x4 acc[4] = {};
          #pragma unroll
          for (int kc = 0; kc < 4; ++kc) {
            acc[0] = __builtin_amdgcn_mfma_f32_16x16x32_f16(wA[ti][kc], bx[0][kc], acc[0], 0, 0, 0);
            acc[1] = __builtin_amdgcn_mfma_f32_16x16x32_f16(wA[ti][kc], bx[1][kc], acc[1], 0, 0, 0);
            acc[2] = __builtin_amdgcn_mfma_f32_16x16x32_f16(wA[ti][kc], bx[2][kc], acc[2], 0, 0, 0);
            acc[3] = __builtin_amdgcn_mfma_f32_16x16x32_f16(wA[ti][kc], bx[3][kc], acc[3], 0, 0, 0);
          }
          #pragma unroll
          for (int sb = 0; sb < 4; ++sb) {
            int s_local = half * 8 + batch * 4 + sb;
            f16x4 o;
            #pragma unroll
            for (int i = 0; i < 4; ++i) o[i] = (_Float16)(acc[sb][i] + bb[ti][i]);
            *(f16x4*)(slab + (size_t)s_local * 12288 + tile * 256 + lq * 64 + lm * 4) = o;
          }
        }
        __syncthreads();                       // drains; xstage reusable
      }
      if (tid == 0)
        __hip_atomic_store(readyP, c + 1, __ATOMIC_RELEASE, __HIP_MEMORY_SCOPE_AGENT);
    }
  }
}

// ---------------- final FC: out[b][c] = hcat[b] . W_fc[c] + b_fc[c] ----------------
__global__ __launch_bounds__(512) void fc_kernel(
    const float* __restrict__ hcat, const float* __restrict__ wfc,
    const float* __restrict__ bfc, float* __restrict__ out)
{
  const int b = blockIdx.x, t = threadIdx.x;
  float h  = hcat[(size_t)b * 512 + t];
  float p0 = h * wfc[t];
  float p1 = h * wfc[512 + t];
  #pragma unroll
  for (int off = 32; off > 0; off >>= 1) {
    p0 += __shfl_down(p0, off);
    p1 += __shfl_down(p1, off);
  }
  __shared__ float s0[8], s1[8];
  if ((t & 63) == 0) { s0[t >> 6] = p0; s1[t >> 6] = p1; }
  __syncthreads();
  if (t == 0) {
    float a = bfc[0], c = bfc[1];
    #pragma unroll
    for (int i = 0; i < 8; ++i) { a += s0[i]; c += s1[i]; }
    out[b * 2 + 0] = a;
    out[b * 2 + 1] = c;
  }
}

extern "C" void kernel_launch(void* const* d_in, const int* in_sizes, int n_in,
                              void* d_out, int out_size, void* d_ws, size_t ws_size,
                              hipStream_t stream)
{
  (void)in_sizes; (void)n_in; (void)out_size; (void)ws_size;
  const int*   seqs  = (const int*)d_in[0];
  const int*   lens  = (const int*)d_in[1];
  const float* embed = (const float*)d_in[2];
  const float* wihf  = (const float*)d_in[3];
  const float* whhf  = (const float*)d_in[4];
  const float* bihf  = (const float*)d_in[5];
  const float* bhhf  = (const float*)d_in[6];
  const float* wihb  = (const float*)d_in[7];
  const float* whhb  = (const float*)d_in[8];
  const float* bihb  = (const float*)d_in[9];
  const float* bhhb  = (const float*)d_in[10];
  const float* wfc   = (const float*)d_in[11];
  const float* bfc   = (const float*)d_in[12];
  float* out = (float*)d_out;

  // workspace layout (~27.4 MB)
  char* ws = (char*)d_ws;
  _Float16* WSW = (_Float16*)ws;                          // 1,179,648 B
  size_t off = 1179648;
  _Float16* XP  = (_Float16*)(ws + off); off += (size_t)2 * 32 * XPSLAB * 2;  // 25,165,824 B
  float* HCAT   = (float*)(ws + off);    off += (size_t)B_ * 2 * H_ * 4;      // 524,288 B
  int* ORDER    = (int*)(ws + off);      off += 1024;
  int* FLAGS    = (int*)(ws + off);      off += 8192;     // ready[1024]+done[512]+hx-cnt[64]
  _Float16* HX  = (_Float16*)(ws + off); off += (size_t)32 * 2 * 2 * 2048 * 2; // 524,288 B

  prep_kernel<<<289, 256, 0, stream>>>(whhf, whhb, wihf, wihb, WSW, lens, ORDER, FLAGS);
  fused_kernel<<<128, 512, 0, stream>>>(WSW, seqs, embed, bihf, bhhf, bihb, bhhb,
                                        lens, ORDER, XP, HX, FLAGS, HCAT);
  fc_kernel<<<B_, 512, 0, stream>>>(HCAT, wfc, bfc, out);
}

// Round 10
// 1147.870 us; speedup vs baseline: 2.7791x; 2.7791x over previous
//
#include <hip/hip_runtime.h>
#include <cstdint>
#include <cstddef>

#define B_   256
#define T_   512
#define E_   128
#define H_   256

typedef _Float16 f16x8 __attribute__((ext_vector_type(8)));
typedef _Float16 f16x4 __attribute__((ext_vector_type(4)));
typedef float    f32x4 __attribute__((ext_vector_type(4)));

// rcp-based fast activations: no div sequence (v_div ~8 ops vs v_rcp 1).
// tanh(x) = 1 - 2/(1+e^{2x}) saturates correctly at +-inf without clamping.
__device__ __forceinline__ float sigm(float x) {
  return __builtin_amdgcn_rcpf(1.f + __expf(-x));
}
__device__ __forceinline__ float tanh_(float x) {
  float e = __expf(2.f * x);
  return 1.f - 2.f * __builtin_amdgcn_rcpf(1.f + e);
}
__device__ __forceinline__ void poll_ge(const int* p, int v) {
  while (__hip_atomic_load(p, __ATOMIC_ACQUIRE, __HIP_MEMORY_SCOPE_AGENT) < v)
    __builtin_amdgcn_s_sleep(4);
}

// ---------------- prep: swizzle weights to MFMA fragment order (fp16) -----------------------
// WSW[dir][kc(12)][tile(48)][lane(64)][8] fp16. kc 0..7: W_hh (K=256), kc 8..11: W_ih (K=128).
// Fragment: lane l supplies W[tile*16+(l&15)][k=(l>>4)*8+j] (8 k-consecutive of row-major W).
// Tiles 0..15 = r rows, 16..31 = z, 32..47 = n.  (verified layout, prior rounds)
// Block 288 additionally does the length-sort + flag init (merged former sort_kernel).
__global__ __launch_bounds__(256) void prep_kernel(
    const float* __restrict__ whhf, const float* __restrict__ whhb,
    const float* __restrict__ wihf, const float* __restrict__ wihb,
    _Float16* __restrict__ WSW,
    const int* __restrict__ lens, int* __restrict__ order, int* __restrict__ flags)
{
  if (blockIdx.x == 288) {
    // rank rows by length (desc) + init flags (ws is re-poisoned each call)
    // FLAGS: [0..1023]  ready slots (g*32 + half*16), init 0
    //        [1024..1535] done slots (1024 + g*16),   init -1
    int i = threadIdx.x;                      // one block of 256
    for (int k = i; k < 1024; k += 256) flags[k] = 0;
    for (int k = i; k < 512;  k += 256) flags[1024 + k] = -1;
    int li = lens[i];
    int rank = 0;
    for (int k = 0; k < B_; ++k) {
      int lk = lens[k];
      rank += (lk > li) || (lk == li && k < i);
    }
    order[rank] = i;
    return;
  }
  int idx = blockIdx.x * 256 + threadIdx.x;   // 288 blocks -> 73728 exactly
  int lane = idx & 63;
  int tile = (idx >> 6) % 48;
  int kc   = (idx / 3072) % 12;
  int dir  = idx / 36864;
  int ncol = tile * 16 + (lane & 15);
  int quad = lane >> 4;
  const float* src;
  if (kc < 8) {
    const float* w = dir ? whhb : whhf;       // [768][256] row-major
    src = w + (size_t)ncol * H_ + kc * 32 + quad * 8;
  } else {
    const float* w = dir ? wihb : wihf;       // [768][128] row-major
    src = w + (size_t)ncol * E_ + (kc - 8) * 32 + quad * 8;
  }
  f16x8 v;
  #pragma unroll
  for (int j = 0; j < 8; ++j) v[j] = (_Float16)src[j];
  *(f16x8*)(WSW + (size_t)idx * 8) = v;
}

// ---------------- fused scan + xp producers, 96 blocks x 512 threads -------------------------
// R9 lesson: cross-CU per-step exchange adds ~2000cyc L2 round-trip to the serial path ->
// 3135us. Back to the R6 single-CU-per-group structure (1070us). R10 single change: the
// register frontier (R3/R8 mapped: weights + ~80 working <= 256/wave) admits FIVE tile-sets
// in AGPR (160), not four: wh[r0,r1,z0,z1,n0] AGPR-parked, only n1 staged in LDS.
// Per-CU LDS reads/step: 192 -> 128 (64 h + 64 n1), cutting ~770cyc off the step's LDS term.
// Arch budget: 96 regs free vs ~80 working demand -> no R8-style spill.
#define XPSLAB 196608        // halfs per (buf,g): 16 s x 12288
__global__ __launch_bounds__(512, 1) void fused_kernel(
    const _Float16* __restrict__ WSW, const int* __restrict__ seqs,
    const float* __restrict__ embed,
    const float* __restrict__ bihf, const float* __restrict__ bhhf,
    const float* __restrict__ bihb, const float* __restrict__ bhhb,
    const int* __restrict__ lens, const int* __restrict__ order,
    _Float16* __restrict__ XP, int* __restrict__ FLAGS, float* __restrict__ hcat)
{
  // union'd LDS arena:
  // consumer: [0,65536) n1 weight frags [w8][kc8][lane64][8]; [65536,82432) hbuf
  // producer: [0,17408) xstage[4][16][136]
  __shared__ __align__(16) char smem[82432];
  __shared__ int s_row[16], s_len[16];

  const int bid = blockIdx.x, tid = threadIdx.x;
  const int w = tid >> 6, lane = tid & 63, lm = lane & 15, lq = lane >> 4;

  if (bid < 32) {
    // ================= CONSUMER =================
    const int g = bid, dir = g & 1, grp = g >> 1;
    _Float16* wl = (_Float16*)smem;                        // n1 frags
    _Float16* hb = (_Float16*)(smem + 65536);              // [buf][chain][264]
    if (tid < 16) { int r = order[grp * 16 + tid]; s_row[tid] = r; s_len[tid] = lens[r]; }
    for (int i = tid; i < 2 * 16 * 264; i += 512) hb[i] = (_Float16)0.f;

    const _Float16* wsd = WSW + (size_t)dir * 294912 + (size_t)lane * 8;
    #pragma unroll
    for (int kc = 0; kc < 8; ++kc)                         // n1 tile -> LDS (own-wave region)
      *(f16x8*)(wl + ((size_t)(w * 8 + kc)) * 512 + lane * 8) =
          *(const f16x8*)(wsd + (size_t)kc * 24576 + (33 + 2 * w) * 512);

    // 5 tile-sets (r0,r1,z0,z1,n0) -> AGPR parking ("+a", proven): 40 frags = 160 AGPRs.
    f16x8 wh[5][8];
    #pragma unroll
    for (int kc = 0; kc < 8; ++kc) {
      wh[0][kc] = *(const f16x8*)(wsd + (size_t)kc * 24576 + (2 * w)      * 512);
      asm volatile("" : "+a"(wh[0][kc]));
      wh[1][kc] = *(const f16x8*)(wsd + (size_t)kc * 24576 + (2 * w + 1)  * 512);
      asm volatile("" : "+a"(wh[1][kc]));
      wh[2][kc] = *(const f16x8*)(wsd + (size_t)kc * 24576 + (16 + 2 * w) * 512);
      asm volatile("" : "+a"(wh[2][kc]));
      wh[3][kc] = *(const f16x8*)(wsd + (size_t)kc * 24576 + (17 + 2 * w) * 512);
      asm volatile("" : "+a"(wh[3][kc]));
      wh[4][kc] = *(const f16x8*)(wsd + (size_t)kc * 24576 + (32 + 2 * w) * 512);
      asm volatile("" : "+a"(wh[4][kc]));
    }
    const float* bhh = dir ? bhhb : bhhf;
    f16x4 bhn[2];                                          // n-gate b_hh, packed f16 (2 VGPRs)
    #pragma unroll
    for (int th = 0; th < 2; ++th) {
      float4 b = *(const float4*)(bhh + 512 + 32 * w + th * 16 + lq * 4);
      bhn[th][0] = (_Float16)b.x; bhn[th][1] = (_Float16)b.y;
      bhn[th][2] = (_Float16)b.z; bhn[th][3] = (_Float16)b.w;
    }
    __syncthreads();
    const int len_l = s_len[lm];
    int ml = 1;
    #pragma unroll
    for (int i = 0; i < 16; ++i) ml = max(ml, s_len[i]);

    int* doneP  = FLAGS + 1024 + g * 16;
    const int* readyA = FLAGS + g * 32;
    const int* readyB = FLAGS + g * 32 + 16;
    float h32r[2][4] = {};

    for (int t = 0; t < ml; ++t) {
      if ((t & 15) == 0) {                     // chunk boundary
        if (tid == 0) {
          if (t) __hip_atomic_store(doneP, (t >> 4) - 1,
                                    __ATOMIC_RELEASE, __HIP_MEMORY_SCOPE_AGENT);
          poll_ge(readyA, (t >> 4) + 1);
          poll_ge(readyB, (t >> 4) + 1);
        }
        __syncthreads();
      }
      // xp for THIS step, issued up front; consumed in the epilogue
      const _Float16* sb = XP + ((size_t)((((t >> 4) & 1) * 32 + g)) * 16 + (t & 15)) * 12288
                           + lq * 64 + lm * 4;
      f16x4 xp[6];
      xp[0] = *(const f16x4*)(sb + (2 * w)      * 256);
      xp[1] = *(const f16x4*)(sb + (2 * w + 1)  * 256);
      xp[2] = *(const f16x4*)(sb + (16 + 2 * w) * 256);
      xp[3] = *(const f16x4*)(sb + (17 + 2 * w) * 256);
      xp[4] = *(const f16x4*)(sb + (32 + 2 * w) * 256);
      xp[5] = *(const f16x4*)(sb + (33 + 2 * w) * 256);

      // n-gate b_hh folded into MFMA C-init (n = tanh(xp_n + r*(Whh_n.h + b_hh_n)))
      f32x4 acc[6] = {};
      #pragma unroll
      for (int i = 0; i < 4; ++i) {
        acc[4][i] = (float)bhn[0][i];
        acc[5][i] = (float)bhn[1][i];
      }
      const _Float16* hrow = hb + ((size_t)(t & 1) * 16 + lm) * 264 + lq * 8;
      #pragma unroll
      for (int kc = 0; kc < 8; ++kc) {
        f16x8 hf = *(const f16x8*)(hrow + kc * 32);
        acc[0] = __builtin_amdgcn_mfma_f32_16x16x32_f16(wh[0][kc], hf, acc[0], 0, 0, 0);
        acc[1] = __builtin_amdgcn_mfma_f32_16x16x32_f16(wh[1][kc], hf, acc[1], 0, 0, 0);
        acc[2] = __builtin_amdgcn_mfma_f32_16x16x32_f16(wh[2][kc], hf, acc[2], 0, 0, 0);
        acc[3] = __builtin_amdgcn_mfma_f32_16x16x32_f16(wh[3][kc], hf, acc[3], 0, 0, 0);
        acc[4] = __builtin_amdgcn_mfma_f32_16x16x32_f16(wh[4][kc], hf, acc[4], 0, 0, 0);
        f16x8 w5 = *(const f16x8*)(wl + ((size_t)(w * 8 + kc)) * 512 + lane * 8);
        acc[5] = __builtin_amdgcn_mfma_f32_16x16x32_f16(w5, hf, acc[5], 0, 0, 0);
      }
      // epilogue: lane = (chain lm, units 32w + th*16 + lq*4 + i). r,z biases folded into xp.
      #pragma unroll
      for (int th = 0; th < 2; ++th) {
        f16x4 pk;
        #pragma unroll
        for (int i = 0; i < 4; ++i) {
          float r = sigm((float)xp[th][i]     + acc[th][i]);
          float z = sigm((float)xp[2 + th][i] + acc[2 + th][i]);
          float n = tanh_((float)xp[4 + th][i] + r * acc[4 + th][i]);
          float hn = (t < len_l) ? (n + z * (h32r[th][i] - n)) : h32r[th][i];
          h32r[th][i] = hn;
          pk[i] = (_Float16)hn;
        }
        *(f16x4*)(hb + ((size_t)((t + 1) & 1) * 16 + lm) * 264 + 32 * w + th * 16 + lq * 4) = pk;
      }
      __syncthreads();                         // h(t+1) visible; only barrier per step
    }
    if (tid == 0)
      __hip_atomic_store(doneP, 999, __ATOMIC_RELEASE, __HIP_MEMORY_SCOPE_AGENT);
    {
      const int rowb = s_row[lm];
      #pragma unroll
      for (int th = 0; th < 2; ++th) {
        float4 o; o.x = h32r[th][0]; o.y = h32r[th][1]; o.z = h32r[th][2]; o.w = h32r[th][3];
        *(float4*)(&hcat[(size_t)rowb * (2 * H_) + dir * H_ + 32 * w + th * 16 + lq * 4]) = o;
      }
    }
  } else {
    // ================= PRODUCER =================
    // XCD-matched mapping: k = bid-32; bid%8 == k%8 == g%8 -> same L2 as consumer g.
    const int k_ = bid - 32;
    const int g = (k_ & 7) + 8 * (k_ >> 4), half = (k_ >> 3) & 1;
    const int dir = g & 1, grp = g >> 1;
    _Float16* xs = (_Float16*)smem;                        // [sb4][chain16][136]
    if (tid < 16) { int r = order[grp * 16 + tid]; s_row[tid] = r; s_len[tid] = lens[r]; }
    __syncthreads();
    int ml = 1;
    #pragma unroll
    for (int i = 0; i < 16; ++i) ml = max(ml, s_len[i]);
    const int nch = (ml + 15) >> 4;

    const int chain = tid >> 5, q = tid & 31;  // x-staging: 32 threads/chain
    const int rowb = s_row[chain], lenr = s_len[chain];
    const _Float16* wsd = WSW + (size_t)dir * 294912 + (size_t)lane * 8;
    const float* bih = dir ? bihb : bihf;
    const float* bhh = dir ? bhhb : bhhf;
    const int* doneP = FLAGS + 1024 + g * 16;
    int* readyP = FLAGS + g * 32 + half * 16;

    // hoist this wave's 6 tiles (w, w+8, ..., w+40): weights + biases to registers
    f16x8 wA[6][4];
    float bb[6][4];
    #pragma unroll
    for (int ti = 0; ti < 6; ++ti) {
      const int tile = w + 8 * ti;
      #pragma unroll
      for (int kc = 0; kc < 4; ++kc)
        wA[ti][kc] = *(const f16x8*)(wsd + (size_t)(8 + kc) * 24576 + tile * 512);
      float4 bias = *(const float4*)(bih + tile * 16 + lq * 4);
      if (tile < 32) {                         // fold b_hh into r,z xp (n stays separate)
        float4 b2 = *(const float4*)(bhh + tile * 16 + lq * 4);
        bias.x += b2.x; bias.y += b2.y; bias.z += b2.z; bias.w += b2.w;
      }
      bb[ti][0] = bias.x; bb[ti][1] = bias.y; bb[ti][2] = bias.z; bb[ti][3] = bias.w;
    }

    for (int c = 0; c < nch; ++c) {
      if (c >= 2) { if (tid == 0) poll_ge(doneP, c - 2); __syncthreads(); }
      _Float16* slab = XP + (size_t)((c & 1) * 32 + g) * XPSLAB;
      #pragma unroll
      for (int batch = 0; batch < 2; ++batch) {
        #pragma unroll
        for (int sb = 0; sb < 4; ++sb) {       // stage x for 4 s-values
          int s = c * 16 + half * 8 + batch * 4 + sb;
          int p = dir ? (lenr - 1 - s) : s;
          p = min(max(p, 0), T_ - 1);
          int tok = seqs[(size_t)rowb * T_ + p];
          float4 f = *(const float4*)(embed + (size_t)tok * E_ + q * 4);
          f16x4 h4; h4[0] = (_Float16)f.x; h4[1] = (_Float16)f.y;
          h4[2] = (_Float16)f.z; h4[3] = (_Float16)f.w;
          *(f16x4*)(xs + ((size_t)sb * 16 + chain) * 136 + q * 4) = h4;
        }
        __syncthreads();
        f16x8 bx[4][4];
        #pragma unroll
        for (int sb = 0; sb < 4; ++sb)
          #pragma unroll
          for (int kc = 0; kc < 4; ++kc)
            bx[sb][kc] = *(const f16x8*)(xs + ((size_t)sb * 16 + lm) * 136 + kc * 32 + lq * 8);
        #pragma unroll
        for (int ti = 0; ti < 6; ++ti) {       // tiles partitioned across waves
          const int tile = w + 8 * ti;
          f32x4 acc[4] = {};
          #pragma unroll
          for (int kc = 0; kc < 4; ++kc) {
            acc[0] = __builtin_amdgcn_mfma_f32_16x16x32_f16(wA[ti][kc], bx[0][kc], acc[0], 0, 0, 0);
            acc[1] = __builtin_amdgcn_mfma_f32_16x16x32_f16(wA[ti][kc], bx[1][kc], acc[1], 0, 0, 0);
            acc[2] = __builtin_amdgcn_mfma_f32_16x16x32_f16(wA[ti][kc], bx[2][kc], acc[2], 0, 0, 0);
            acc[3] = __builtin_amdgcn_mfma_f32_16x16x32_f16(wA[ti][kc], bx[3][kc], acc[3], 0, 0, 0);
          }
          #pragma unroll
          for (int sb = 0; sb < 4; ++sb) {
            int s_local = half * 8 + batch * 4 + sb;
            f16x4 o;
            #pragma unroll
            for (int i = 0; i < 4; ++i) o[i] = (_Float16)(acc[sb][i] + bb[ti][i]);
            *(f16x4*)(slab + (size_t)s_local * 12288 + tile * 256 + lq * 64 + lm * 4) = o;
          }
        }
        __syncthreads();                       // drains; xstage reusable
      }
      if (tid == 0)
        __hip_atomic_store(readyP, c + 1, __ATOMIC_RELEASE, __HIP_MEMORY_SCOPE_AGENT);
    }
  }
}

// ---------------- final FC: out[b][c] = hcat[b] . W_fc[c] + b_fc[c] ----------------
__global__ __launch_bounds__(512) void fc_kernel(
    const float* __restrict__ hcat, const float* __restrict__ wfc,
    const float* __restrict__ bfc, float* __restrict__ out)
{
  const int b = blockIdx.x, t = threadIdx.x;
  float h  = hcat[(size_t)b * 512 + t];
  float p0 = h * wfc[t];
  float p1 = h * wfc[512 + t];
  #pragma unroll
  for (int off = 32; off > 0; off >>= 1) {
    p0 += __shfl_down(p0, off);
    p1 += __shfl_down(p1, off);
  }
  __shared__ float s0[8], s1[8];
  if ((t & 63) == 0) { s0[t >> 6] = p0; s1[t >> 6] = p1; }
  __syncthreads();
  if (t == 0) {
    float a = bfc[0], c = bfc[1];
    #pragma unroll
    for (int i = 0; i < 8; ++i) { a += s0[i]; c += s1[i]; }
    out[b * 2 + 0] = a;
    out[b * 2 + 1] = c;
  }
}

extern "C" void kernel_launch(void* const* d_in, const int* in_sizes, int n_in,
                              void* d_out, int out_size, void* d_ws, size_t ws_size,
                              hipStream_t stream)
{
  (void)in_sizes; (void)n_in; (void)out_size; (void)ws_size;
  const int*   seqs  = (const int*)d_in[0];
  const int*   lens  = (const int*)d_in[1];
  const float* embed = (const float*)d_in[2];
  const float* wihf  = (const float*)d_in[3];
  const float* whhf  = (const float*)d_in[4];
  const float* bihf  = (const float*)d_in[5];
  const float* bhhf  = (const float*)d_in[6];
  const float* wihb  = (const float*)d_in[7];
  const float* whhb  = (const float*)d_in[8];
  const float* bihb  = (const float*)d_in[9];
  const float* bhhb  = (const float*)d_in[10];
  const float* wfc   = (const float*)d_in[11];
  const float* bfc   = (const float*)d_in[12];
  float* out = (float*)d_out;

  // workspace layout (~25.6 MB)
  char* ws = (char*)d_ws;
  _Float16* WSW = (_Float16*)ws;                          // 1,179,648 B
  size_t off = 1179648;
  _Float16* XP  = (_Float16*)(ws + off); off += (size_t)2 * 32 * XPSLAB * 2;  // 25,165,824 B
  float* HCAT   = (float*)(ws + off);    off += (size_t)B_ * 2 * H_ * 4;      // 524,288 B
  int* ORDER    = (int*)(ws + off);      off += 1024;
  int* FLAGS    = (int*)(ws + off);      off += 6144;     // ready[1024] + done[512]

  prep_kernel<<<289, 256, 0, stream>>>(whhf, whhb, wihf, wihb, WSW, lens, ORDER, FLAGS);
  fused_kernel<<<96, 512, 0, stream>>>(WSW, seqs, embed, bihf, bhhf, bihb, bhhb,
                                       lens, ORDER, XP, FLAGS, HCAT);
  fc_kernel<<<B_, 512, 0, stream>>>(HCAT, wfc, bfc, out);
}